// Round 27
// baseline (105.768 us; speedup 1.0000x reference)
//
#include <hip/hip_runtime.h>
#include <stdint.h>

#define BATCH 32
#define CH    256
#define TLEN  4096
#define TN    32
#define NT    8             // tiles per block (block covers 256 t)
#define NRW   36            // sA rows per tile: t0-2 .. t0+33
#define TPAD  4100          // aT rows per batch strip: 2 pad + 4096 + 2 pad
#define SST   36            // phase-B f32 scratch row stride

typedef short    bf16x8 __attribute__((ext_vector_type(8)));
typedef float    f32x4  __attribute__((ext_vector_type(4)));
typedef uint16_t u16x4  __attribute__((ext_vector_type(4)));
typedef uint16_t u16x8  __attribute__((ext_vector_type(8)));

// packed fragment-order weights: g_wpk[(s*CH + co)*32 + g*8 + e] = w1eff[co][32s+8g+e]
__device__ __attribute__((aligned(16))) uint16_t g_wpk[CH * CH];
__device__ __attribute__((aligned(16))) float g_tap[5 * CH];   // tap-major
__device__ __attribute__((aligned(16))) float g_bias[CH];

static __device__ __forceinline__ uint16_t f32_to_bf16(float f) {
    uint32_t u = __builtin_bit_cast(uint32_t, f);
    u += 0x7FFFu + ((u >> 16) & 1u);
    return (uint16_t)(u >> 16);
}
static __device__ __forceinline__ float bf16_to_f32(uint16_t h) {
    uint32_t u = ((uint32_t)h) << 16;
    return __builtin_bit_cast(float, u);
}
// tanh-form gelu folded into exp2
static __device__ __forceinline__ float gelu_fast(float x) {
    const float A = 2.3022082f;
    const float B = 0.10294331f;
    float x2 = x * x;
    float z  = x * fmaf(x2, B, A);
    float e  = exp2f(z);
    float r  = __builtin_amdgcn_rcpf(1.0f + e);
    return fmaf(-x, r, x);
}

__global__ void prep_kernel(const float* __restrict__ w1, const float* __restrict__ b1,
                            const float* __restrict__ w3, const float* __restrict__ b3,
                            const float* __restrict__ w5, const float* __restrict__ b5,
                            const float* __restrict__ wc, const float* __restrict__ bc) {
    const int o = blockIdx.x;
    const int c = threadIdx.x;
    const float wc0 = wc[o * 3 + 0];
    const int s = c >> 5, g = (c >> 3) & 3, e = c & 7;
    g_wpk[(s * CH + o) * 32 + g * 8 + e] = f32_to_bf16(wc0 * w1[o * CH + c]);
    if (c == 0) {
        const float wc1 = wc[o * 3 + 1], wc2 = wc[o * 3 + 2];
        g_tap[0 * CH + o] = wc2 * w5[o * 5 + 0];
        g_tap[1 * CH + o] = wc1 * w3[o * 3 + 0] + wc2 * w5[o * 5 + 1];
        g_tap[2 * CH + o] = wc1 * w3[o * 3 + 1] + wc2 * w5[o * 5 + 2];
        g_tap[3 * CH + o] = wc1 * w3[o * 3 + 2] + wc2 * w5[o * 5 + 3];
        g_tap[4 * CH + o] = wc2 * w5[o * 5 + 4];
        g_bias[o] = wc0 * b1[o] + wc1 * b3[o] + wc2 * b5[o] + bc[o];
    }
}

// k1: gelu + cast + transpose into aT[b][strip_row][c] bf16, where
// strip_row = 2 + t, element (t,c) stored at col c ^ ((t&7)<<3).
// sL swizzle: element (c=cr, t) lives at sL[cr*72 + ((t&7) | (((t>>3)^(cr>>3))<<3))]
__global__ __launch_bounds__(256, 4)
void gelu_tr_kernel(const float* __restrict__ x, uint16_t* __restrict__ aT) {
    __shared__ __attribute__((aligned(16))) uint16_t sL[64 * 72];   // 9216 B

    const int tid = threadIdx.x;
    const int tb = blockIdx.x, cb = blockIdx.y, b = blockIdx.z;
    const int t0 = tb * 64, c0 = cb * 64;

    {
        const int cr = tid >> 2;       // 0..63 channel-local
        const int q  = tid & 3;        // 0..3 t-quarter (16 t)
        const float* xr = x + ((size_t)(b * CH + c0 + cr)) * TLEN + t0 + q * 16;
        f32x4 v0 = *(const f32x4*)(xr + 0);
        f32x4 v1 = *(const f32x4*)(xr + 4);
        f32x4 v2 = *(const f32x4*)(xr + 8);
        f32x4 v3 = *(const f32x4*)(xr + 12);
        u16x8 p0, p1;
#pragma unroll
        for (int j = 0; j < 4; ++j) {
            p0[j]     = f32_to_bf16(gelu_fast(v0[j]));
            p0[4 + j] = f32_to_bf16(gelu_fast(v1[j]));
            p1[j]     = f32_to_bf16(gelu_fast(v2[j]));
            p1[4 + j] = f32_to_bf16(gelu_fast(v3[j]));
        }
        const int b0 = (((q * 2 + 0) ^ (cr >> 3)) << 3);
        const int b1 = (((q * 2 + 1) ^ (cr >> 3)) << 3);
        *(u16x8*)(&sL[cr * 72 + b0]) = p0;
        *(u16x8*)(&sL[cr * 72 + b1]) = p1;
    }
    __syncthreads();

    uint16_t* aTb = aT + (size_t)b * TPAD * CH;
#pragma unroll
    for (int i = 0; i < 2; ++i) {
        const int idx = tid + i * 256;
        const int tr  = idx >> 3;      // 0..63
        const int ch  = idx & 7;       // 0..7 c-chunk
        const int t   = t0 + tr;
        const int swz = (t & 7) << 3;
        const int cin = (tr & 7) | ((((tr >> 3) ^ ch) & 7) << 3);
        u16x8 o;
#pragma unroll
        for (int j = 0; j < 8; ++j) o[j] = sL[(ch * 8 + j) * 72 + cin];
        *(u16x8*)(&aTb[(size_t)(2 + t) * CH + ((c0 + ch * 8) ^ swz)]) = o;
    }
    if (tb == 0) {
        const int pr = tid >> 6;       // 0..3
        const int cc = c0 + (tid & 63);
        const int prow = (pr < 2) ? pr : (4098 + (pr - 2));
        const int tmod = (pr < 2) ? (6 + pr) : (pr - 2);   // (t&7) of the pad row
        aTb[(size_t)prow * CH + (cc ^ (tmod << 3))] = 0;
    }
}

// k2: persistent 8-tile march, dedicated phase-B scratch (1 barrier/tile),
// depth-2 K-loop ds_read prefetch (3-slot rotation), commit-early (sA[nxt]
// LDS commit right after phase A so lgkm drain overlaps phase B stores).
// 512 threads = 8 waves, each owning M=32 channels. Weights in regs.
// sA row r <-> t = t0 + r - 2; swizzle of row r = ((r+6)&7)<<3.
__global__ __launch_bounds__(512, 2)
void gemm_kernel(const uint16_t* __restrict__ aT, const float* __restrict__ x,
                 float* __restrict__ out) {
    __shared__ __attribute__((aligned(16))) uint16_t sA[2][NRW * CH];  // 36864 B
    __shared__ __attribute__((aligned(16))) float    sS[8 * 16 * SST]; // 18432 B

    const int tid  = threadIdx.x;
    const int lane = tid & 63;
    const int wid  = tid >> 6;         // 0..7
    const int b    = blockIdx.y;
    const int t0b  = blockIdx.x * (TN * NT);

    const float* __restrict__ xb = x + (size_t)b * CH * TLEN;
    float* __restrict__ ob = out + (size_t)b * CH * TLEN;
    const u16x8* __restrict__ gB = (const u16x8*)(aT + (size_t)b * TPAD * CH);

    const int m0   = wid * 32;         // wave's 32-channel group
    const int colt = lane & 15;
    const int kgrp = (lane >> 4) * 8;
    const int rg   = (lane >> 4) * 4;
    const int ci   = lane >> 2;        // 0..15 channel-local (phase B)
    const int q4   = lane & 3;         // 0..3 -> 8 t each    (phase B)
    const bool tail = (tid < 128);

    // ---- weight panel into registers FIRST ----
    bf16x8 wfr[8][2];
#pragma unroll
    for (int s = 0; s < 8; ++s)
#pragma unroll
        for (int mi = 0; mi < 2; ++mi) {
            const int co = m0 + mi * 16 + colt;
            wfr[s][mi] = *(const bf16x8*)(g_wpk + (s * CH + co) * 32 + kgrp);
        }

    // ---- prologue: stage tile 0 into sA[0] ----
    {
        const u16x8* g0 = gB + (size_t)t0b * 32;
        u16x8 s0_ = g0[tid];
        u16x8 s1_ = g0[tid + 512];
        u16x8 sT_;
        if (tail) sT_ = g0[tid + 1024];
        u16x8* d = (u16x8*)sA[0];
        d[tid] = s0_; d[tid + 512] = s1_;
        if (tail) d[tid + 1024] = sT_;
    }
    __syncthreads();   // B1 (tile 0 ready)

    const int swzB = (colt & 7) << 3;
    int rowB[2];
#pragma unroll
    for (int ni = 0; ni < 2; ++ni) rowB[ni] = (ni * 16 + colt + 2) * CH;
    int swzA[5];
#pragma unroll
    for (int k = 0; k < 5; ++k) swzA[k] = ((colt + k + 6) & 7) << 3;

    for (int i = 0; i < NT; ++i) {
        const int cur = i & 1, nxt = cur ^ 1;
        const int t0 = t0b + i * TN;

        // ---- issue prefetches: tile i+1 staging chunks + tile i residual ----
        u16x8 p0, p1, pT;
        if (i + 1 < NT) {
            const u16x8* gn = gB + (size_t)(t0 + TN) * 32;
            p0 = gn[tid];
            p1 = gn[tid + 512];
            if (tail) pT = gn[tid + 1024];
        }
        f32x4 xv[2][2];
#pragma unroll
        for (int mi = 0; mi < 2; ++mi) {
            const int cc = m0 + mi * 16 + ci;
            const float* xr = xb + (size_t)cc * TLEN + t0 + q4 * 8;
            xv[mi][0] = *(const f32x4*)(xr + 0);
            xv[mi][1] = *(const f32x4*)(xr + 4);
        }

        const uint16_t* __restrict__ sAc = sA[cur];

        f32x4 acc[2][2];
        const f32x4 vzero = {0.f, 0.f, 0.f, 0.f};
#pragma unroll
        for (int mi = 0; mi < 2; ++mi)
#pragma unroll
            for (int ni = 0; ni < 2; ++ni) acc[mi][ni] = vzero;

        // ---- K loop: depth-2 ds_read prefetch (3-slot rotation) + MFMA ----
        bf16x8 bfb[3][2];
#pragma unroll
        for (int ni = 0; ni < 2; ++ni)
            bfb[0][ni] = *(const bf16x8*)(&sAc[rowB[ni] + (kgrp ^ swzB)]);
#pragma unroll
        for (int ni = 0; ni < 2; ++ni)
            bfb[1][ni] = *(const bf16x8*)(&sAc[rowB[ni] + ((32 + kgrp) ^ swzB)]);
#pragma unroll
        for (int s = 0; s < 8; ++s) {
            const int cu = s % 3, pf = (s + 2) % 3;
            if (s < 6) {
                const int cin = (s + 2) * 32 + kgrp;
#pragma unroll
                for (int ni = 0; ni < 2; ++ni)
                    bfb[pf][ni] = *(const bf16x8*)(&sAc[rowB[ni] + (cin ^ swzB)]);
            }
#pragma unroll
            for (int mi = 0; mi < 2; ++mi)
#pragma unroll
                for (int ni = 0; ni < 2; ++ni)
                    acc[mi][ni] = __builtin_amdgcn_mfma_f32_16x16x32_bf16(wfr[s][mi], bfb[cu][ni], acc[mi][ni], 0, 0, 0);
        }

        // ---- phase A: depthwise + bias folded into acc ----
#pragma unroll
        for (int mi = 0; mi < 2; ++mi) {
            const int c = m0 + mi * 16 + rg;
            const f32x4 tp0 = *(const f32x4*)(g_tap + 0 * CH + c);
            const f32x4 tp1 = *(const f32x4*)(g_tap + 1 * CH + c);
            const f32x4 tp2 = *(const f32x4*)(g_tap + 2 * CH + c);
            const f32x4 tp3 = *(const f32x4*)(g_tap + 3 * CH + c);
            const f32x4 tp4 = *(const f32x4*)(g_tap + 4 * CH + c);
            const f32x4 bsv = *(const f32x4*)(g_bias + c);
#pragma unroll
            for (int ni = 0; ni < 2; ++ni) {
                const int t = ni * 16 + colt;
                u16x4 a0 = *(const u16x4*)(&sAc[(t + 0) * CH + (c ^ swzA[0])]);
                u16x4 a1 = *(const u16x4*)(&sAc[(t + 1) * CH + (c ^ swzA[1])]);
                u16x4 a2 = *(const u16x4*)(&sAc[(t + 2) * CH + (c ^ swzA[2])]);
                u16x4 a3 = *(const u16x4*)(&sAc[(t + 3) * CH + (c ^ swzA[3])]);
                u16x4 a4 = *(const u16x4*)(&sAc[(t + 4) * CH + (c ^ swzA[4])]);
#pragma unroll
                for (int r = 0; r < 4; ++r) {
                    float d = tp0[r] * bf16_to_f32(a0[r]);
                    d = fmaf(tp1[r], bf16_to_f32(a1[r]), d);
                    d = fmaf(tp2[r], bf16_to_f32(a2[r]), d);
                    d = fmaf(tp3[r], bf16_to_f32(a3[r]), d);
                    d = fmaf(tp4[r], bf16_to_f32(a4[r]), d);
                    acc[mi][ni][r] += d + bsv[r];
                }
            }
        }

        // ---- commit-early: prefetched tile i+1 into sA[nxt] (safe: all reads of
        //      sA[nxt] ended before the previous B1; its readers start after next B1) ----
        if (i + 1 < NT) {
            u16x8* d = (u16x8*)sA[nxt];
            d[tid] = p0; d[tid + 512] = p1;
            if (tail) d[tid + 1024] = pT;
        }

        // ---- phase B: wave-private transpose through sS (no barrier needed) ----
        float* __restrict__ sw = sS + wid * (16 * SST);   // 2304 B per wave
#pragma unroll
        for (int mi = 0; mi < 2; ++mi) {
#pragma unroll
            for (int ni = 0; ni < 2; ++ni) {
                const int t = ni * 16 + colt;
#pragma unroll
                for (int r = 0; r < 4; ++r) sw[(rg + r) * SST + t] = acc[mi][ni][r];
            }
            const int cc = m0 + mi * 16 + ci;
            float* orow = ob + (size_t)cc * TLEN + t0 + q4 * 8;
            const float* srow = sw + ci * SST + q4 * 8;
            f32x4 s0 = *(const f32x4*)(srow + 0);
            f32x4 s1 = *(const f32x4*)(srow + 4);
            *(f32x4*)(orow + 0) = s0 + xv[mi][0];
            *(f32x4*)(orow + 4) = s1 + xv[mi][1];
        }

        __syncthreads();   // B1: sA[nxt] ready for tile i+1
    }
}

extern "C" void kernel_launch(void* const* d_in, const int* in_sizes, int n_in,
                              void* d_out, int out_size, void* d_ws, size_t ws_size,
                              hipStream_t stream) {
    const float* x  = (const float*)d_in[0];
    const float* w1 = (const float*)d_in[1];
    const float* b1 = (const float*)d_in[2];
    const float* w3 = (const float*)d_in[3];
    const float* b3 = (const float*)d_in[4];
    const float* w5 = (const float*)d_in[5];
    const float* b5 = (const float*)d_in[6];
    const float* wc = (const float*)d_in[7];
    const float* bc = (const float*)d_in[8];
    float* out = (float*)d_out;
    uint16_t* aT = (uint16_t*)d_ws;    // 32*4100*256*2 B = 67.2 MB

    prep_kernel<<<dim3(CH), dim3(CH), 0, stream>>>(w1, b1, w3, b3, w5, b5, wc, bc);
    gelu_tr_kernel<<<dim3(TLEN / 64, CH / 64, BATCH), dim3(256), 0, stream>>>(x, aT);
    gemm_kernel<<<dim3(TLEN / (TN * NT), BATCH), dim3(512), 0, stream>>>(aT, x, out);
}

// Round 28
// 98.545 us; speedup vs baseline: 1.0733x; 1.0733x over previous
//
#include <hip/hip_runtime.h>
#include <stdint.h>

#define BATCH 32
#define CH    256
#define TLEN  4096
#define TN    32
#define NT    8             // tiles per block (block covers 256 t)
#define NRW   36            // sA rows per tile: t0-2 .. t0+33
#define TPAD  4100          // aT rows per batch strip: 2 pad + 4096 + 2 pad
#define SST   36            // phase-B f32 scratch row stride

typedef short    bf16x8 __attribute__((ext_vector_type(8)));
typedef float    f32x4  __attribute__((ext_vector_type(4)));
typedef uint16_t u16x4  __attribute__((ext_vector_type(4)));
typedef uint16_t u16x8  __attribute__((ext_vector_type(8)));

// packed fragment-order weights: g_wpk[(s*CH + co)*32 + g*8 + e] = w1eff[co][32s+8g+e]
__device__ __attribute__((aligned(16))) uint16_t g_wpk[CH * CH];
__device__ __attribute__((aligned(16))) float g_tap[5 * CH];   // tap-major
__device__ __attribute__((aligned(16))) float g_bias[CH];

static __device__ __forceinline__ uint16_t f32_to_bf16(float f) {
    uint32_t u = __builtin_bit_cast(uint32_t, f);
    u += 0x7FFFu + ((u >> 16) & 1u);
    return (uint16_t)(u >> 16);
}
static __device__ __forceinline__ float bf16_to_f32(uint16_t h) {
    uint32_t u = ((uint32_t)h) << 16;
    return __builtin_bit_cast(float, u);
}
// tanh-form gelu folded into exp2
static __device__ __forceinline__ float gelu_fast(float x) {
    const float A = 2.3022082f;
    const float B = 0.10294331f;
    float x2 = x * x;
    float z  = x * fmaf(x2, B, A);
    float e  = exp2f(z);
    float r  = __builtin_amdgcn_rcpf(1.0f + e);
    return fmaf(-x, r, x);
}

// k1: gelu + cast + transpose into aT[b][strip_row][c] bf16, where
// strip_row = 2 + t, element (t,c) stored at col c ^ ((t&7)<<3).
// sL swizzle: element (c=cr, t) lives at sL[cr*72 + ((t&7) | (((t>>3)^(cr>>3))<<3))]
// PREP MERGED: blocks with b==0 additionally build g_wpk/g_tap/g_bias for
// output channel o = tb*4+cb (no dependency on k1's own output; k2 launches
// only after all of k1 completes, so g_* is ready).
__global__ __launch_bounds__(256, 4)
void gelu_tr_kernel(const float* __restrict__ x, uint16_t* __restrict__ aT,
                    const float* __restrict__ w1, const float* __restrict__ b1,
                    const float* __restrict__ w3, const float* __restrict__ b3,
                    const float* __restrict__ w5, const float* __restrict__ b5,
                    const float* __restrict__ wc, const float* __restrict__ bc) {
    __shared__ __attribute__((aligned(16))) uint16_t sL[64 * 72];   // 9216 B

    const int tid = threadIdx.x;
    const int tb = blockIdx.x, cb = blockIdx.y, b = blockIdx.z;
    const int t0 = tb * 64, c0 = cb * 64;

    // ---- merged prep (256 blocks of the b==0 slice, one output channel each) ----
    if (b == 0) {
        const int o = tb * 4 + cb;     // 0..255
        const int c = tid;
        const float wc0 = wc[o * 3 + 0];
        const int s = c >> 5, g = (c >> 3) & 3, e = c & 7;
        g_wpk[(s * CH + o) * 32 + g * 8 + e] = f32_to_bf16(wc0 * w1[o * CH + c]);
        if (c == 0) {
            const float wc1 = wc[o * 3 + 1], wc2 = wc[o * 3 + 2];
            g_tap[0 * CH + o] = wc2 * w5[o * 5 + 0];
            g_tap[1 * CH + o] = wc1 * w3[o * 3 + 0] + wc2 * w5[o * 5 + 1];
            g_tap[2 * CH + o] = wc1 * w3[o * 3 + 1] + wc2 * w5[o * 5 + 2];
            g_tap[3 * CH + o] = wc1 * w3[o * 3 + 2] + wc2 * w5[o * 5 + 3];
            g_tap[4 * CH + o] = wc2 * w5[o * 5 + 4];
            g_bias[o] = wc0 * b1[o] + wc1 * b3[o] + wc2 * b5[o] + bc[o];
        }
    }

    {
        const int cr = tid >> 2;       // 0..63 channel-local
        const int q  = tid & 3;        // 0..3 t-quarter (16 t)
        const float* xr = x + ((size_t)(b * CH + c0 + cr)) * TLEN + t0 + q * 16;
        f32x4 v0 = *(const f32x4*)(xr + 0);
        f32x4 v1 = *(const f32x4*)(xr + 4);
        f32x4 v2 = *(const f32x4*)(xr + 8);
        f32x4 v3 = *(const f32x4*)(xr + 12);
        u16x8 p0, p1;
#pragma unroll
        for (int j = 0; j < 4; ++j) {
            p0[j]     = f32_to_bf16(gelu_fast(v0[j]));
            p0[4 + j] = f32_to_bf16(gelu_fast(v1[j]));
            p1[j]     = f32_to_bf16(gelu_fast(v2[j]));
            p1[4 + j] = f32_to_bf16(gelu_fast(v3[j]));
        }
        const int b0 = (((q * 2 + 0) ^ (cr >> 3)) << 3);
        const int b1_ = (((q * 2 + 1) ^ (cr >> 3)) << 3);
        *(u16x8*)(&sL[cr * 72 + b0])  = p0;
        *(u16x8*)(&sL[cr * 72 + b1_]) = p1;
    }
    __syncthreads();

    uint16_t* aTb = aT + (size_t)b * TPAD * CH;
#pragma unroll
    for (int i = 0; i < 2; ++i) {
        const int idx = tid + i * 256;
        const int tr  = idx >> 3;      // 0..63
        const int ch  = idx & 7;       // 0..7 c-chunk
        const int t   = t0 + tr;
        const int swz = (t & 7) << 3;
        const int cin = (tr & 7) | ((((tr >> 3) ^ ch) & 7) << 3);
        u16x8 o;
#pragma unroll
        for (int j = 0; j < 8; ++j) o[j] = sL[(ch * 8 + j) * 72 + cin];
        *(u16x8*)(&aTb[(size_t)(2 + t) * CH + ((c0 + ch * 8) ^ swz)]) = o;
    }
    if (tb == 0) {
        const int pr = tid >> 6;       // 0..3
        const int cc = c0 + (tid & 63);
        const int prow = (pr < 2) ? pr : (4098 + (pr - 2));
        const int tmod = (pr < 2) ? (6 + pr) : (pr - 2);   // (t&7) of the pad row
        aTb[(size_t)prow * CH + (cc ^ (tmod << 3))] = 0;
    }
}

// k2 (r26, best measured): persistent 8-tile march, dedicated phase-B scratch
// (1 barrier/tile), 1-deep K-loop ping-pong, commit-late. 512 threads = 8
// waves, each owning M=32 channels. Weights in regs (wfr[8][2], loaded once).
// sA row r <-> t = t0 + r - 2; swizzle of row r = ((r+6)&7)<<3.
__global__ __launch_bounds__(512, 2)
void gemm_kernel(const uint16_t* __restrict__ aT, const float* __restrict__ x,
                 float* __restrict__ out) {
    __shared__ __attribute__((aligned(16))) uint16_t sA[2][NRW * CH];  // 36864 B
    __shared__ __attribute__((aligned(16))) float    sS[8 * 16 * SST]; // 18432 B

    const int tid  = threadIdx.x;
    const int lane = tid & 63;
    const int wid  = tid >> 6;         // 0..7
    const int b    = blockIdx.y;
    const int t0b  = blockIdx.x * (TN * NT);

    const float* __restrict__ xb = x + (size_t)b * CH * TLEN;
    float* __restrict__ ob = out + (size_t)b * CH * TLEN;
    const u16x8* __restrict__ gB = (const u16x8*)(aT + (size_t)b * TPAD * CH);

    const int m0   = wid * 32;         // wave's 32-channel group
    const int colt = lane & 15;
    const int kgrp = (lane >> 4) * 8;
    const int rg   = (lane >> 4) * 4;
    const int ci   = lane >> 2;        // 0..15 channel-local (phase B)
    const int q4   = lane & 3;         // 0..3 -> 8 t each    (phase B)
    const bool tail = (tid < 128);

    // ---- weight panel into registers FIRST ----
    bf16x8 wfr[8][2];
#pragma unroll
    for (int s = 0; s < 8; ++s)
#pragma unroll
        for (int mi = 0; mi < 2; ++mi) {
            const int co = m0 + mi * 16 + colt;
            wfr[s][mi] = *(const bf16x8*)(g_wpk + (s * CH + co) * 32 + kgrp);
        }

    // ---- prologue: stage tile 0 into sA[0] ----
    {
        const u16x8* g0 = gB + (size_t)t0b * 32;
        u16x8 s0_ = g0[tid];
        u16x8 s1_ = g0[tid + 512];
        u16x8 sT_;
        if (tail) sT_ = g0[tid + 1024];
        u16x8* d = (u16x8*)sA[0];
        d[tid] = s0_; d[tid + 512] = s1_;
        if (tail) d[tid + 1024] = sT_;
    }
    __syncthreads();   // B1 (tile 0 ready)

    const int swzB = (colt & 7) << 3;
    int rowB[2];
#pragma unroll
    for (int ni = 0; ni < 2; ++ni) rowB[ni] = (ni * 16 + colt + 2) * CH;
    int swzA[5];
#pragma unroll
    for (int k = 0; k < 5; ++k) swzA[k] = ((colt + k + 6) & 7) << 3;

    for (int i = 0; i < NT; ++i) {
        const int cur = i & 1, nxt = cur ^ 1;
        const int t0 = t0b + i * TN;

        // ---- issue prefetches: tile i+1 staging chunks + tile i residual ----
        u16x8 p0, p1, pT;
        if (i + 1 < NT) {
            const u16x8* gn = gB + (size_t)(t0 + TN) * 32;
            p0 = gn[tid];
            p1 = gn[tid + 512];
            if (tail) pT = gn[tid + 1024];
        }
        f32x4 xv[2][2];
#pragma unroll
        for (int mi = 0; mi < 2; ++mi) {
            const int cc = m0 + mi * 16 + ci;
            const float* xr = xb + (size_t)cc * TLEN + t0 + q4 * 8;
            xv[mi][0] = *(const f32x4*)(xr + 0);
            xv[mi][1] = *(const f32x4*)(xr + 4);
        }

        const uint16_t* __restrict__ sAc = sA[cur];

        f32x4 acc[2][2];
        const f32x4 vzero = {0.f, 0.f, 0.f, 0.f};
#pragma unroll
        for (int mi = 0; mi < 2; ++mi)
#pragma unroll
            for (int ni = 0; ni < 2; ++ni) acc[mi][ni] = vzero;

        // ---- K loop: pure LDS ping-pong + MFMA (weights from regs) ----
        bf16x8 bfb[2][2];
#pragma unroll
        for (int ni = 0; ni < 2; ++ni)
            bfb[0][ni] = *(const bf16x8*)(&sAc[rowB[ni] + (kgrp ^ swzB)]);
#pragma unroll
        for (int s = 0; s < 8; ++s) {
            const int c2 = s & 1, nx = c2 ^ 1;
            if (s < 7) {
                const int cin = (s + 1) * 32 + kgrp;
#pragma unroll
                for (int ni = 0; ni < 2; ++ni)
                    bfb[nx][ni] = *(const bf16x8*)(&sAc[rowB[ni] + (cin ^ swzB)]);
            }
#pragma unroll
            for (int mi = 0; mi < 2; ++mi)
#pragma unroll
                for (int ni = 0; ni < 2; ++ni)
                    acc[mi][ni] = __builtin_amdgcn_mfma_f32_16x16x32_bf16(wfr[s][mi], bfb[c2][ni], acc[mi][ni], 0, 0, 0);
        }

        // ---- phase A: depthwise + bias folded into acc ----
#pragma unroll
        for (int mi = 0; mi < 2; ++mi) {
            const int c = m0 + mi * 16 + rg;
            const f32x4 tp0 = *(const f32x4*)(g_tap + 0 * CH + c);
            const f32x4 tp1 = *(const f32x4*)(g_tap + 1 * CH + c);
            const f32x4 tp2 = *(const f32x4*)(g_tap + 2 * CH + c);
            const f32x4 tp3 = *(const f32x4*)(g_tap + 3 * CH + c);
            const f32x4 tp4 = *(const f32x4*)(g_tap + 4 * CH + c);
            const f32x4 bsv = *(const f32x4*)(g_bias + c);
#pragma unroll
            for (int ni = 0; ni < 2; ++ni) {
                const int t = ni * 16 + colt;
                u16x4 a0 = *(const u16x4*)(&sAc[(t + 0) * CH + (c ^ swzA[0])]);
                u16x4 a1 = *(const u16x4*)(&sAc[(t + 1) * CH + (c ^ swzA[1])]);
                u16x4 a2 = *(const u16x4*)(&sAc[(t + 2) * CH + (c ^ swzA[2])]);
                u16x4 a3 = *(const u16x4*)(&sAc[(t + 3) * CH + (c ^ swzA[3])]);
                u16x4 a4 = *(const u16x4*)(&sAc[(t + 4) * CH + (c ^ swzA[4])]);
#pragma unroll
                for (int r = 0; r < 4; ++r) {
                    float d = tp0[r] * bf16_to_f32(a0[r]);
                    d = fmaf(tp1[r], bf16_to_f32(a1[r]), d);
                    d = fmaf(tp2[r], bf16_to_f32(a2[r]), d);
                    d = fmaf(tp3[r], bf16_to_f32(a3[r]), d);
                    d = fmaf(tp4[r], bf16_to_f32(a4[r]), d);
                    acc[mi][ni][r] += d + bsv[r];
                }
            }
        }

        // ---- phase B: wave-private transpose through sS (no barrier needed) ----
        float* __restrict__ sw = sS + wid * (16 * SST);   // 2304 B per wave
#pragma unroll
        for (int mi = 0; mi < 2; ++mi) {
#pragma unroll
            for (int ni = 0; ni < 2; ++ni) {
                const int t = ni * 16 + colt;
#pragma unroll
                for (int r = 0; r < 4; ++r) sw[(rg + r) * SST + t] = acc[mi][ni][r];
            }
            const int cc = m0 + mi * 16 + ci;
            float* orow = ob + (size_t)cc * TLEN + t0 + q4 * 8;
            const float* srow = sw + ci * SST + q4 * 8;
            f32x4 s0 = *(const f32x4*)(srow + 0);
            f32x4 s1 = *(const f32x4*)(srow + 4);
            *(f32x4*)(orow + 0) = s0 + xv[mi][0];
            *(f32x4*)(orow + 4) = s1 + xv[mi][1];
        }

        // ---- commit prefetched tile i+1 into sA[nxt] ----
        if (i + 1 < NT) {
            u16x8* d = (u16x8*)sA[nxt];
            d[tid] = p0; d[tid + 512] = p1;
            if (tail) d[tid + 1024] = pT;
        }
        __syncthreads();   // B1: sA[nxt] ready for tile i+1
    }
}

extern "C" void kernel_launch(void* const* d_in, const int* in_sizes, int n_in,
                              void* d_out, int out_size, void* d_ws, size_t ws_size,
                              hipStream_t stream) {
    const float* x  = (const float*)d_in[0];
    const float* w1 = (const float*)d_in[1];
    const float* b1 = (const float*)d_in[2];
    const float* w3 = (const float*)d_in[3];
    const float* b3 = (const float*)d_in[4];
    const float* w5 = (const float*)d_in[5];
    const float* b5 = (const float*)d_in[6];
    const float* wc = (const float*)d_in[7];
    const float* bc = (const float*)d_in[8];
    float* out = (float*)d_out;
    uint16_t* aT = (uint16_t*)d_ws;    // 32*4100*256*2 B = 67.2 MB

    gelu_tr_kernel<<<dim3(TLEN / 64, CH / 64, BATCH), dim3(256), 0, stream>>>(
        x, aT, w1, b1, w3, b3, w5, b5, wc, bc);
    gemm_kernel<<<dim3(TLEN / (TN * NT), BATCH), dim3(512), 0, stream>>>(aT, x, out);
}